// Round 1
// baseline (394.425 us; speedup 1.0000x reference)
//
#include <hip/hip_runtime.h>
#include <math.h>

#define BB 32
#define GG 15
#define KK 2048
#define NBG (BB*GG)          // 480
#define N1F 983040.0f        // B*G*K
#define EPS 1e-5f

// ---- workspace layout (float offsets) ----
#define WS_SREL  0       // 8   (6 used) second moments of rel, atomically accumulated
#define WS_SUMS1 8       // 64  sum h2 (stage1 layer2)
#define WS_SQS1  72      // 64  sum h2^2
#define WS_ST2A  136     // 256 stage2 layer1 stats (sum[128], sumsq[128])
#define WS_ST2B  392     // 256 stage2 layer2 stats
#define WS_ST3A  648     // 512 stage3 layer1 stats
#define WS_ST3B  1160    // 512 stage3 layer2 stats
#define WS_ZERON 1672    // everything above must be zeroed each launch
#define WS_A1    1672    // 64   layer1 BN scale (g*rsqrt(var))
#define WS_CENT  1736    // 1440 centroids (b,g,3)
#define WS_MAX   3176    // 30720 per-(b,g,o) max of h2
#define WS_MIN   33896   // 30720 min
#define WS_LF1T  64616   // 30720 lf1 transposed (b,g,64)
#define WS_C2    95336   // 480  (b,5,3)
#define WS_C3    95816   // 96   (b,3)
#define WS_F2    95912   // 32160 feats2 (480 pos, 67)
#define WS_H2A   128072  // 61440 stage2 layer1 pre-BN
#define WS_H2B   189512  // 61440 stage2 layer2 pre-BN
#define WS_F3    250952  // 20960 feats3 (160 pos, 131)
#define WS_H3A   271912  // 40960
#define WS_H3B   312872  // 40960

__device__ const int SIDX[15] = {0,1,8, 2,4,6, 3,5,7, 9,11,13, 10,12,14};

__device__ __forceinline__ float wave_sum(float v){
    for (int off = 32; off; off >>= 1) v += __shfl_down(v, off, 64);
    return v;
}

// K1: centroids + 3x3 second moments of rel. grid=480, block=256
__global__ void __launch_bounds__(256) k1_pass1(const float* __restrict__ x,
                                                float* __restrict__ ws,
                                                float* __restrict__ out) {
    int bg = blockIdx.x, tid = threadIdx.x;
    const float* xp = x + (size_t)bg * KK * 3;
    float s0=0,s1=0,s2=0,p00=0,p11=0,p22=0,p01=0,p02=0,p12=0;
    for (int k = tid; k < KK; k += 256) {
        float a = xp[k*3+0], b = xp[k*3+1], c = xp[k*3+2];
        s0+=a; s1+=b; s2+=c;
        p00=fmaf(a,a,p00); p11=fmaf(b,b,p11); p22=fmaf(c,c,p22);
        p01=fmaf(a,b,p01); p02=fmaf(a,c,p02); p12=fmaf(b,c,p12);
    }
    __shared__ float red[9*4];
    float vals[9] = {s0,s1,s2,p00,p11,p22,p01,p02,p12};
    int lane = tid & 63, wv = tid >> 6;
    #pragma unroll
    for (int q = 0; q < 9; q++) {
        float v = wave_sum(vals[q]);
        if (lane == 0) red[q*4+wv] = v;
    }
    __syncthreads();
    if (tid == 0) {
        float t[9];
        #pragma unroll
        for (int q = 0; q < 9; q++) t[q] = red[q*4]+red[q*4+1]+red[q*4+2]+red[q*4+3];
        float c0 = t[0]/KK, c1 = t[1]/KK, c2 = t[2]/KK;
        ws[WS_CENT+bg*3+0]=c0; ws[WS_CENT+bg*3+1]=c1; ws[WS_CENT+bg*3+2]=c2;
        int b = bg / GG, g = bg % GG;
        out[8192 + b*(67*GG) + 0*GG + g] = c0;
        out[8192 + b*(67*GG) + 1*GG + g] = c1;
        out[8192 + b*(67*GG) + 2*GG + g] = c2;
        atomicAdd(&ws[WS_SREL+0], t[3] - KK*c0*c0);
        atomicAdd(&ws[WS_SREL+1], t[4] - KK*c1*c1);
        atomicAdd(&ws[WS_SREL+2], t[5] - KK*c2*c2);
        atomicAdd(&ws[WS_SREL+3], t[6] - KK*c0*c1);
        atomicAdd(&ws[WS_SREL+4], t[7] - KK*c0*c2);
        atomicAdd(&ws[WS_SREL+5], t[8] - KK*c1*c2);
    }
}

// K2: layer1 BN scale a1[o] = g0*rsqrt(W0 S W0^T + eps). 1 block x 64
__global__ void k2_prep(const float* __restrict__ w0, const float* __restrict__ g0,
                        float* __restrict__ ws) {
    int o = threadIdx.x;
    float S00=ws[WS_SREL+0]/N1F, S11=ws[WS_SREL+1]/N1F, S22=ws[WS_SREL+2]/N1F;
    float S01=ws[WS_SREL+3]/N1F, S02=ws[WS_SREL+4]/N1F, S12=ws[WS_SREL+5]/N1F;
    float w0o=w0[o*3+0], w1o=w0[o*3+1], w2o=w0[o*3+2];
    float var = w0o*w0o*S00 + w1o*w1o*S11 + w2o*w2o*S22
              + 2.f*(w0o*w1o*S01 + w0o*w2o*S02 + w1o*w2o*S12);
    ws[WS_A1+o] = g0[o]*rsqrtf(var + EPS);
}

// K3: main fused pass — v=relu(BN(W0@rel)); h2=W1@v; track max/min/sum/sumsq of h2.
// grid=480 (one (b,g)), block=256. Thread roles:
//   v-role:      i_ch = tid&63, kk-group = tid>>6 (8 kk each of a 32-k chunk)
//   gemm-role:   o5 = tid&31 (owns channels o5 and o5+32), q = tid>>5 (k-quad)
__global__ void __launch_bounds__(256, 2) k3_pass2(
        const float* __restrict__ x, const float* __restrict__ w0,
        const float* __restrict__ b0, const float* __restrict__ w1,
        float* __restrict__ ws) {
    __shared__ __align__(16) float xs[96];
    __shared__ __align__(16) float vbuf[2048];   // v[kk][i], kk<32, i<64
    int bg = blockIdx.x, tid = threadIdx.x;
    const float* xp = x + (size_t)bg * KK * 3;
    float c0 = ws[WS_CENT+bg*3+0], c1 = ws[WS_CENT+bg*3+1], c2 = ws[WS_CENT+bg*3+2];

    int ich = tid & 63, g8 = tid >> 6;
    float w00 = w0[ich*3+0], w01 = w0[ich*3+1], w02 = w0[ich*3+2];
    float a1i = ws[WS_A1+ich], b0i = b0[ich];

    int o5 = tid & 31, q = tid >> 5;
    float w1a[64], w1b[64];
    #pragma unroll
    for (int i = 0; i < 64; i++) {
        w1a[i] = w1[o5*64 + i];
        w1b[i] = w1[(o5+32)*64 + i];
    }
    float mxA=-1e30f, mnA=1e30f, smA=0.f, sqA=0.f;
    float mxB=-1e30f, mnB=1e30f, smB=0.f, sqB=0.f;

    for (int chunk = 0; chunk < 64; chunk++) {
        int kb = chunk * 32;
        __syncthreads();                       // vbuf/xs safe to overwrite
        if (tid < 96) xs[tid] = xp[kb*3 + tid];
        __syncthreads();
        #pragma unroll
        for (int j = 0; j < 8; j++) {
            int kk = g8*8 + j;
            float r0 = xs[kk*3+0]-c0, r1 = xs[kk*3+1]-c1, r2 = xs[kk*3+2]-c2;
            float pre = fmaf(a1i, fmaf(w00,r0, fmaf(w01,r1, w02*r2)), b0i);
            vbuf[kk*64 + ich] = fmaxf(pre, 0.f);
        }
        __syncthreads();
        float accA[4] = {0,0,0,0}, accB[4] = {0,0,0,0};
        #pragma unroll
        for (int i0 = 0; i0 < 64; i0 += 4) {
            #pragma unroll
            for (int kk2 = 0; kk2 < 4; kk2++) {
                float4 v4 = *reinterpret_cast<const float4*>(&vbuf[(q*4+kk2)*64 + i0]);
                float a = accA[kk2];
                a = fmaf(w1a[i0+0], v4.x, a);
                a = fmaf(w1a[i0+1], v4.y, a);
                a = fmaf(w1a[i0+2], v4.z, a);
                a = fmaf(w1a[i0+3], v4.w, a);
                accA[kk2] = a;
                float b = accB[kk2];
                b = fmaf(w1b[i0+0], v4.x, b);
                b = fmaf(w1b[i0+1], v4.y, b);
                b = fmaf(w1b[i0+2], v4.z, b);
                b = fmaf(w1b[i0+3], v4.w, b);
                accB[kk2] = b;
            }
        }
        #pragma unroll
        for (int kk2 = 0; kk2 < 4; kk2++) {
            float hA = accA[kk2], hB = accB[kk2];
            mxA = fmaxf(mxA,hA); mnA = fminf(mnA,hA); smA += hA; sqA = fmaf(hA,hA,sqA);
            mxB = fmaxf(mxB,hB); mnB = fminf(mnB,hB); smB += hB; sqB = fmaf(hB,hB,sqB);
        }
    }
    __syncthreads();
    vbuf[0*256+tid]=mxA; vbuf[1*256+tid]=mnA; vbuf[2*256+tid]=smA; vbuf[3*256+tid]=sqA;
    vbuf[4*256+tid]=mxB; vbuf[5*256+tid]=mnB; vbuf[6*256+tid]=smB; vbuf[7*256+tid]=sqB;
    __syncthreads();
    if (tid < 64) {
        int o = tid, base = (o < 32) ? o : o-32, qo = (o < 32) ? 0 : 4;
        float mx=-1e30f, mn=1e30f, sm=0.f, sq=0.f;
        #pragma unroll
        for (int qq = 0; qq < 8; qq++) {
            int ii = qq*32 + base;
            mx = fmaxf(mx, vbuf[(qo+0)*256+ii]);
            mn = fminf(mn, vbuf[(qo+1)*256+ii]);
            sm += vbuf[(qo+2)*256+ii];
            sq += vbuf[(qo+3)*256+ii];
        }
        ws[WS_MAX+bg*64+o] = mx;
        ws[WS_MIN+bg*64+o] = mn;
        atomicAdd(&ws[WS_SUMS1+o], sm);
        atomicAdd(&ws[WS_SQS1+o], sq);
    }
}

// K4: lf1 = relu(BN(max/min h2)) using monotonicity. grid=480, block=64
__global__ void k4_final(const float* __restrict__ g1, const float* __restrict__ b1,
                         float* __restrict__ ws, float* __restrict__ out) {
    int bg = blockIdx.x, o = threadIdx.x;
    float mean = ws[WS_SUMS1+o] / N1F;
    float var  = ws[WS_SQS1+o] / N1F - mean*mean;
    float s = g1[o]*rsqrtf(var + EPS);
    float t = b1[o] - mean*s;
    float sel = (s >= 0.f) ? ws[WS_MAX+bg*64+o] : ws[WS_MIN+bg*64+o];
    float val = fmaxf(fmaf(s, sel, t), 0.f);
    int b = bg / GG, g = bg % GG;
    out[8192 + b*(67*GG) + (3+o)*GG + g] = val;
    ws[WS_LF1T + bg*64 + o] = val;
}

// K5: build c2, c3, feats2. grid=32, block=128
__global__ void k5_build2(float* __restrict__ ws) {
    int b = blockIdx.x, tid = threadIdx.x;
    __shared__ float c2ls[15];
    if (tid < 15) {
        int s = tid/3, i = tid%3;
        float acc = 0.f;
        for (int j = 0; j < 3; j++) {
            int g = SIDX[s*3+j];
            acc += ws[WS_CENT + (b*GG+g)*3 + i];
        }
        acc *= (1.f/3.f);
        c2ls[tid] = acc;
        ws[WS_C2 + b*15 + tid] = acc;
    }
    __syncthreads();
    if (tid < 3) {
        float acc = 0.f;
        for (int s = 0; s < 5; s++) acc += c2ls[s*3+tid];
        ws[WS_C3 + b*3 + tid] = acc * 0.2f;
    }
    for (int it = tid; it < 1005; it += 128) {
        int p = it / 67, c = it % 67;
        int s = p/3, j = p%3, g = SIDX[s*3+j];
        float val;
        if (c < 3) val = ws[WS_CENT + (b*GG+g)*3 + c] - c2ls[s*3+c];
        else       val = ws[WS_LF1T + (b*GG+g)*64 + (c-3)];
        ws[WS_F2 + (b*15+p)*67 + c] = val;
    }
}

// K6: stage2 layer1 matmul + stats. grid=120 (4 pos each), block=128
__global__ void k6_s2l1(const float* __restrict__ w, float* __restrict__ ws) {
    int p0 = blockIdx.x*4, o = threadIdx.x;
    float sum=0.f, sq=0.f;
    for (int pp = 0; pp < 4; pp++) {
        int p = p0+pp;
        float acc = 0.f;
        for (int c = 0; c < 67; c++) acc = fmaf(w[o*67+c], ws[WS_F2+p*67+c], acc);
        ws[WS_H2A + p*128 + o] = acc;
        sum += acc; sq = fmaf(acc,acc,sq);
    }
    atomicAdd(&ws[WS_ST2A+o], sum);
    atomicAdd(&ws[WS_ST2A+128+o], sq);
}

// K7: stage2 BN+relu then layer2 matmul + stats. grid=60 (8 pos), block=128
__global__ void k7_s2l2(const float* __restrict__ g0, const float* __restrict__ b0,
                        const float* __restrict__ w1, float* __restrict__ ws) {
    int p0 = blockIdx.x*8, o = threadIdx.x;
    __shared__ float vls[8*128];
    float mean = ws[WS_ST2A+o]/480.f;
    float var  = ws[WS_ST2A+128+o]/480.f - mean*mean;
    float s = g0[o]*rsqrtf(var+EPS);
    float t = b0[o] - mean*s;
    for (int pp = 0; pp < 8; pp++)
        vls[pp*128+o] = fmaxf(fmaf(s, ws[WS_H2A+(p0+pp)*128+o], t), 0.f);
    __syncthreads();
    float sum=0.f, sq=0.f;
    for (int pp = 0; pp < 8; pp++) {
        float acc = 0.f;
        for (int i = 0; i < 128; i++) acc = fmaf(w1[o*128+i], vls[pp*128+i], acc);
        ws[WS_H2B+(p0+pp)*128+o] = acc;
        sum += acc; sq = fmaf(acc,acc,sq);
    }
    atomicAdd(&ws[WS_ST2B+o], sum);
    atomicAdd(&ws[WS_ST2B+128+o], sq);
}

// K8: lf2 = max_j relu(BN(h2)); build feats3. grid=32, block=128
__global__ void k8_build3(const float* __restrict__ g1, const float* __restrict__ b1,
                          float* __restrict__ ws) {
    int b = blockIdx.x, o = threadIdx.x;
    float mean = ws[WS_ST2B+o]/480.f;
    float var  = ws[WS_ST2B+128+o]/480.f - mean*mean;
    float s = g1[o]*rsqrtf(var+EPS);
    float t = b1[o] - mean*s;
    for (int s5 = 0; s5 < 5; s5++) {
        float m = -1e30f;
        for (int j = 0; j < 3; j++) {
            float v = fmaxf(fmaf(s, ws[WS_H2B+((b*5+s5)*3+j)*128+o], t), 0.f);
            m = fmaxf(m, v);
        }
        ws[WS_F3 + (b*5+s5)*131 + 3 + o] = m;
    }
    if (o < 15) {
        int s5 = o/3, i = o%3;
        ws[WS_F3 + (b*5+s5)*131 + i] = ws[WS_C2+b*15+o] - ws[WS_C3+b*3+i];
    }
}

// K9: stage3 layer1. grid=40 (4 pos), block=256
__global__ void k9_s3l1(const float* __restrict__ w, float* __restrict__ ws) {
    int p0 = blockIdx.x*4, o = threadIdx.x;
    float sum=0.f, sq=0.f;
    for (int pp = 0; pp < 4; pp++) {
        int p = p0+pp;
        float acc = 0.f;
        for (int c = 0; c < 131; c++) acc = fmaf(w[o*131+c], ws[WS_F3+p*131+c], acc);
        ws[WS_H3A + p*256 + o] = acc;
        sum += acc; sq = fmaf(acc,acc,sq);
    }
    atomicAdd(&ws[WS_ST3A+o], sum);
    atomicAdd(&ws[WS_ST3A+256+o], sq);
}

// K10: stage3 BN+relu + layer2. grid=40 (4 pos), block=256
__global__ void k10_s3l2(const float* __restrict__ g0, const float* __restrict__ b0,
                         const float* __restrict__ w1, float* __restrict__ ws) {
    int p0 = blockIdx.x*4, o = threadIdx.x;
    __shared__ float vls[4*256];
    float mean = ws[WS_ST3A+o]/160.f;
    float var  = ws[WS_ST3A+256+o]/160.f - mean*mean;
    float s = g0[o]*rsqrtf(var+EPS);
    float t = b0[o] - mean*s;
    for (int pp = 0; pp < 4; pp++)
        vls[pp*256+o] = fmaxf(fmaf(s, ws[WS_H3A+(p0+pp)*256+o], t), 0.f);
    __syncthreads();
    float sum=0.f, sq=0.f;
    for (int pp = 0; pp < 4; pp++) {
        float acc = 0.f;
        for (int i = 0; i < 256; i++) acc = fmaf(w1[o*256+i], vls[pp*256+i], acc);
        ws[WS_H3B+(p0+pp)*256+o] = acc;
        sum += acc; sq = fmaf(acc,acc,sq);
    }
    atomicAdd(&ws[WS_ST3B+o], sum);
    atomicAdd(&ws[WS_ST3B+256+o], sq);
}

// K11: gf = max_jj relu(BN(h2)). grid=32, block=256
__global__ void k11_gf(const float* __restrict__ g1, const float* __restrict__ b1,
                       const float* __restrict__ ws, float* __restrict__ out) {
    int b = blockIdx.x, o = threadIdx.x;
    float mean = ws[WS_ST3B+o]/160.f;
    float var  = ws[WS_ST3B+256+o]/160.f - mean*mean;
    float s = g1[o]*rsqrtf(var+EPS);
    float t = b1[o] - mean*s;
    float m = -1e30f;
    for (int jj = 0; jj < 5; jj++)
        m = fmaxf(m, fmaxf(fmaf(s, ws[WS_H3B+(b*5+jj)*256+o], t), 0.f));
    out[b*256+o] = m;
}

extern "C" void kernel_launch(void* const* d_in, const int* in_sizes, int n_in,
                              void* d_out, int out_size, void* d_ws, size_t ws_size,
                              hipStream_t stream) {
    (void)in_sizes; (void)n_in; (void)out_size; (void)ws_size;
    const float* x   = (const float*)d_in[0];
    const float* w00 = (const float*)d_in[1];
    const float* g00 = (const float*)d_in[2];
    const float* b00 = (const float*)d_in[3];
    const float* w01 = (const float*)d_in[4];
    const float* g01 = (const float*)d_in[5];
    const float* b01 = (const float*)d_in[6];
    const float* w10 = (const float*)d_in[7];
    const float* g10 = (const float*)d_in[8];
    const float* b10 = (const float*)d_in[9];
    const float* w11 = (const float*)d_in[10];
    const float* g11 = (const float*)d_in[11];
    const float* b11 = (const float*)d_in[12];
    const float* w20 = (const float*)d_in[13];
    const float* g20 = (const float*)d_in[14];
    const float* b20 = (const float*)d_in[15];
    const float* w21 = (const float*)d_in[16];
    const float* g21 = (const float*)d_in[17];
    const float* b21 = (const float*)d_in[18];
    float* out = (float*)d_out;
    float* ws  = (float*)d_ws;

    hipMemsetAsync(ws, 0, WS_ZERON*sizeof(float), stream);
    k1_pass1<<<NBG, 256, 0, stream>>>(x, ws, out);
    k2_prep <<<1, 64, 0, stream>>>(w00, g00, ws);
    k3_pass2<<<NBG, 256, 0, stream>>>(x, w00, b00, w01, ws);
    k4_final<<<NBG, 64, 0, stream>>>(g01, b01, ws, out);
    k5_build2<<<BB, 128, 0, stream>>>(ws);
    k6_s2l1 <<<120, 128, 0, stream>>>(w10, ws);
    k7_s2l2 <<<60, 128, 0, stream>>>(g10, b10, w11, ws);
    k8_build3<<<BB, 128, 0, stream>>>(g11, b11, ws);
    k9_s3l1 <<<40, 256, 0, stream>>>(w20, ws);
    k10_s3l2<<<40, 256, 0, stream>>>(g20, b20, w21, ws);
    k11_gf  <<<BB, 256, 0, stream>>>(g21, b21, ws, out);
}

// Round 2
// 285.583 us; speedup vs baseline: 1.3811x; 1.3811x over previous
//
#include <hip/hip_runtime.h>
#include <math.h>

#define BB 32
#define GG 15
#define KK 2048
#define NBG (BB*GG)          // 480
#define N1F 983040.0f        // B*G*K
#define EPS 1e-5f
#define SPLITS 4
#define KSPL (KK/SPLITS)     // 512
#define KC 64                // k-positions per chunk
#define NCH (KSPL/KC)        // 8
#define VST 72               // halfs per LDS row (144B: 16B-aligned, 2-way banks = free)

// ---- workspace layout (float offsets) ----
// zeroed region
#define WS_SREL  0       // 8 (6 used)
#define WS_SUMS1 8       // 256 = 4 splits x 64
#define WS_SQS1  264     // 256
#define WS_ST2A  520     // 256
#define WS_ST2B  776     // 256
#define WS_ST3A  1032    // 512
#define WS_ST3B  1544    // 512
#define WS_ZERON 2056
// persistent
#define WS_CENT  2056    // 1440
#define WS_C2    3496    // 480
#define WS_C3    3976    // 96
#define WS_F2    4072    // 32160 -> ends 36232
// MAX/MIN written by k3, read by k45; then region reused by tail buffers
#define WS_MAX   36232   // 4*480*64 = 122880 -> ends 159112
#define WS_MIN   159112  // 122880 -> ends 281992
// tail overlays (written strictly after k45 consumed MAX/MIN)
#define WS_H2A   36232   // 61440  (over MAX)
#define WS_H2B   97672   // 61440  (over MAX)
#define WS_F3    159112  // 20960  (over MIN)
#define WS_H3A   180072  // 40960  (over MIN)
#define WS_H3B   221032  // 40960  (over MIN, ends 261992 < 281992)

typedef _Float16 half8 __attribute__((ext_vector_type(8)));
typedef float f32x4 __attribute__((ext_vector_type(4)));

__device__ const int SIDX[15] = {0,1,8, 2,4,6, 3,5,7, 9,11,13, 10,12,14};

__device__ __forceinline__ float wave_sum(float v){
    for (int off = 32; off; off >>= 1) v += __shfl_down(v, off, 64);
    return v;
}

// K1: centroids + 3x3 second moments of rel. grid=480, block=256
__global__ void __launch_bounds__(256) k1_pass1(const float* __restrict__ x,
                                                float* __restrict__ ws,
                                                float* __restrict__ out) {
    int bg = blockIdx.x, tid = threadIdx.x;
    const float* xp = x + (size_t)bg * KK * 3;
    float s0=0,s1=0,s2=0,p00=0,p11=0,p22=0,p01=0,p02=0,p12=0;
    for (int k = tid; k < KK; k += 256) {
        float a = xp[k*3+0], b = xp[k*3+1], c = xp[k*3+2];
        s0+=a; s1+=b; s2+=c;
        p00=fmaf(a,a,p00); p11=fmaf(b,b,p11); p22=fmaf(c,c,p22);
        p01=fmaf(a,b,p01); p02=fmaf(a,c,p02); p12=fmaf(b,c,p12);
    }
    __shared__ float red[9*4];
    float vals[9] = {s0,s1,s2,p00,p11,p22,p01,p02,p12};
    int lane = tid & 63, wv = tid >> 6;
    #pragma unroll
    for (int q = 0; q < 9; q++) {
        float v = wave_sum(vals[q]);
        if (lane == 0) red[q*4+wv] = v;
    }
    __syncthreads();
    if (tid == 0) {
        float t[9];
        #pragma unroll
        for (int q = 0; q < 9; q++) t[q] = red[q*4]+red[q*4+1]+red[q*4+2]+red[q*4+3];
        float c0 = t[0]/KK, c1 = t[1]/KK, c2 = t[2]/KK;
        ws[WS_CENT+bg*3+0]=c0; ws[WS_CENT+bg*3+1]=c1; ws[WS_CENT+bg*3+2]=c2;
        int b = bg / GG, g = bg % GG;
        out[8192 + b*(67*GG) + 0*GG + g] = c0;
        out[8192 + b*(67*GG) + 1*GG + g] = c1;
        out[8192 + b*(67*GG) + 2*GG + g] = c2;
        atomicAdd(&ws[WS_SREL+0], t[3] - KK*c0*c0);
        atomicAdd(&ws[WS_SREL+1], t[4] - KK*c1*c1);
        atomicAdd(&ws[WS_SREL+2], t[5] - KK*c2*c2);
        atomicAdd(&ws[WS_SREL+3], t[6] - KK*c0*c1);
        atomicAdd(&ws[WS_SREL+4], t[7] - KK*c0*c2);
        atomicAdd(&ws[WS_SREL+5], t[8] - KK*c1*c2);
    }
}

// K3: MFMA fused pass. grid = NBG*SPLITS = 1920, block = 256 (4 waves).
// Each block: one (bg, k-split of 512). h2 = W1(64x64) @ V(64x512) via
// mfma_f32_16x16x32_f16; wave w owns o-rows [16w,16w+16). Tracks per-o
// max/min/sum/sumsq of fp32 h2.
__global__ void __launch_bounds__(256) k3_mfma(
        const float* __restrict__ x,  const float* __restrict__ w0,
        const float* __restrict__ b0, const float* __restrict__ g0,
        const float* __restrict__ w1, float* __restrict__ ws) {
    __shared__ __align__(16) _Float16 vB[KC*VST];  // 9216 B, [k][i] fp16
    __shared__ __align__(16) float xs[KC*3];       // 768 B
    __shared__ float sredM[64], sredN[64], sredS[64], sredQ[64];

    int tid = threadIdx.x;
    int bg  = blockIdx.x >> 2;
    int spl = blockIdx.x & 3;
    const float* xp = x + (size_t)bg*KK*3 + (size_t)spl*KSPL*3;

    float c0 = ws[WS_CENT+bg*3+0], c1 = ws[WS_CENT+bg*3+1], c2 = ws[WS_CENT+bg*3+2];

    // --- layer1 BN scale (inlined k2) for this thread's input channel ---
    int ich = tid & 63;
    float w00 = w0[ich*3+0], w01 = w0[ich*3+1], w02 = w0[ich*3+2];
    float S00=ws[WS_SREL+0]/N1F, S11=ws[WS_SREL+1]/N1F, S22=ws[WS_SREL+2]/N1F;
    float S01=ws[WS_SREL+3]/N1F, S02=ws[WS_SREL+4]/N1F, S12=ws[WS_SREL+5]/N1F;
    float var1 = w00*w00*S00 + w01*w01*S11 + w02*w02*S22
               + 2.f*(w00*w01*S01 + w00*w02*S02 + w01*w02*S12);
    float a1i = g0[ich]*rsqrtf(var1 + EPS);
    float b0i = b0[ich];

    int wv = tid >> 6, lane = tid & 63, l15 = lane & 15, quad = lane >> 4;

    // --- A-frags: W1 o-rows for this wave, fp16. A[m=l15][k_i=quad*8+j] ---
    half8 afrag[2];
    #pragma unroll
    for (int c = 0; c < 2; c++)
        #pragma unroll
        for (int j = 0; j < 8; j++)
            afrag[c][j] = (_Float16)w1[(wv*16 + l15)*64 + c*32 + quad*8 + j];

    float mx[4], mn[4], sm[4], sq[4];
    #pragma unroll
    for (int r = 0; r < 4; r++) { mx[r]=-1e30f; mn[r]=1e30f; sm[r]=0.f; sq[r]=0.f; }

    for (int ch = 0; ch < NCH; ch++) {
        int kb = ch * KC;
        __syncthreads();                       // vB/xs safe to overwrite
        if (tid < 48)
            *reinterpret_cast<float4*>(&xs[tid*4]) =
                *reinterpret_cast<const float4*>(&xp[kb*3 + tid*4]);
        __syncthreads();
        // v-compute: thread's channel ich, k rows kk = wv + 4t
        #pragma unroll
        for (int t = 0; t < 16; t++) {
            int kk = wv + 4*t;
            float r0 = xs[kk*3+0]-c0, r1 = xs[kk*3+1]-c1, r2 = xs[kk*3+2]-c2;
            float pre = fmaf(a1i, fmaf(w00,r0, fmaf(w01,r1, w02*r2)), b0i);
            vB[kk*VST + ich] = (_Float16)fmaxf(pre, 0.f);
        }
        __syncthreads();
        // MFMA: 4 k-tiles of 16, contraction i=64 in 2 chunks of 32
        #pragma unroll
        for (int kt = 0; kt < 4; kt++) {
            const _Float16* row = &vB[(kt*16 + l15)*VST + quad*8];
            half8 bf0 = *reinterpret_cast<const half8*>(row);
            half8 bf1 = *reinterpret_cast<const half8*>(row + 32);
            f32x4 acc = {0.f, 0.f, 0.f, 0.f};
            acc = __builtin_amdgcn_mfma_f32_16x16x32_f16(afrag[0], bf0, acc, 0, 0, 0);
            acc = __builtin_amdgcn_mfma_f32_16x16x32_f16(afrag[1], bf1, acc, 0, 0, 0);
            #pragma unroll
            for (int r = 0; r < 4; r++) {
                float h = acc[r];   // o = wv*16 + quad*4 + r, k = kt*16 + l15
                mx[r] = fmaxf(mx[r], h); mn[r] = fminf(mn[r], h);
                sm[r] += h;              sq[r] = fmaf(h, h, sq[r]);
            }
        }
    }
    // reduce over the 16 lanes (bits 0..3) sharing the same quad
    #pragma unroll
    for (int m = 1; m < 16; m <<= 1) {
        #pragma unroll
        for (int r = 0; r < 4; r++) {
            mx[r] = fmaxf(mx[r], __shfl_xor(mx[r], m, 64));
            mn[r] = fminf(mn[r], __shfl_xor(mn[r], m, 64));
            sm[r] += __shfl_xor(sm[r], m, 64);
            sq[r] += __shfl_xor(sq[r], m, 64);
        }
    }
    if (l15 == 0) {
        int o = wv*16 + quad*4;
        #pragma unroll
        for (int r = 0; r < 4; r++) {
            sredM[o+r]=mx[r]; sredN[o+r]=mn[r]; sredS[o+r]=sm[r]; sredQ[o+r]=sq[r];
        }
    }
    __syncthreads();
    if (tid < 64) {
        size_t slot = (size_t)(spl*NBG + bg)*64 + tid;
        ws[WS_MAX + slot] = sredM[tid];
        ws[WS_MIN + slot] = sredN[tid];
        atomicAdd(&ws[WS_SUMS1 + spl*64 + tid], sredS[tid]);
        atomicAdd(&ws[WS_SQS1  + spl*64 + tid], sredQ[tid]);
    }
}

// K45: fused lf1 finalize + c2/c3/feats2 build. grid=32 (per b), block=128
__global__ void k45_final(const float* __restrict__ g1, const float* __restrict__ b1,
                          float* __restrict__ ws, float* __restrict__ out) {
    int b = blockIdx.x, tid = threadIdx.x;
    __shared__ float sA[64], tA[64], lf1[960], c2ls[15];
    if (tid < 64) {
        int o = tid;
        float smv=0.f, sqv=0.f;
        #pragma unroll
        for (int s = 0; s < SPLITS; s++) {
            smv += ws[WS_SUMS1 + s*64 + o];
            sqv += ws[WS_SQS1  + s*64 + o];
        }
        float mean = smv / N1F;
        float var  = sqv / N1F - mean*mean;
        float s1 = g1[o]*rsqrtf(var + EPS);
        sA[o] = s1; tA[o] = b1[o] - mean*s1;
    }
    __syncthreads();
    for (int idx = tid; idx < 960; idx += 128) {
        int g = idx >> 6, o = idx & 63;
        int bg = b*GG + g;
        float s1 = sA[o], t1 = tA[o];
        float sel;
        if (s1 >= 0.f) {
            float v = -1e30f;
            #pragma unroll
            for (int s = 0; s < SPLITS; s++)
                v = fmaxf(v, ws[WS_MAX + (size_t)(s*NBG+bg)*64 + o]);
            sel = v;
        } else {
            float v = 1e30f;
            #pragma unroll
            for (int s = 0; s < SPLITS; s++)
                v = fminf(v, ws[WS_MIN + (size_t)(s*NBG+bg)*64 + o]);
            sel = v;
        }
        float val = fmaxf(fmaf(s1, sel, t1), 0.f);
        lf1[idx] = val;
        out[8192 + b*(67*GG) + (3+o)*GG + g] = val;
    }
    if (tid < 15) {
        int s = tid/3, i = tid%3;
        float acc = 0.f;
        for (int j = 0; j < 3; j++) {
            int g = SIDX[s*3+j];
            acc += ws[WS_CENT + (b*GG+g)*3 + i];
        }
        acc *= (1.f/3.f);
        c2ls[tid] = acc;
        ws[WS_C2 + b*15 + tid] = acc;
    }
    __syncthreads();
    if (tid < 3) {
        float acc = 0.f;
        for (int s = 0; s < 5; s++) acc += c2ls[s*3+tid];
        ws[WS_C3 + b*3 + tid] = acc * 0.2f;
    }
    for (int it = tid; it < 1005; it += 128) {
        int p = it / 67, c = it % 67;
        int s = p/3, j = p%3, g = SIDX[s*3+j];
        float val;
        if (c < 3) val = ws[WS_CENT + (b*GG+g)*3 + c] - c2ls[s*3+c];
        else       val = lf1[g*64 + (c-3)];
        ws[WS_F2 + (b*15+p)*67 + c] = val;
    }
}

// K6: stage2 layer1 matmul + stats. grid=120 (4 pos each), block=128
__global__ void k6_s2l1(const float* __restrict__ w, float* __restrict__ ws) {
    int p0 = blockIdx.x*4, o = threadIdx.x;
    float sum=0.f, sq=0.f;
    for (int pp = 0; pp < 4; pp++) {
        int p = p0+pp;
        float acc = 0.f;
        for (int c = 0; c < 67; c++) acc = fmaf(w[o*67+c], ws[WS_F2+p*67+c], acc);
        ws[WS_H2A + p*128 + o] = acc;
        sum += acc; sq = fmaf(acc,acc,sq);
    }
    atomicAdd(&ws[WS_ST2A+o], sum);
    atomicAdd(&ws[WS_ST2A+128+o], sq);
}

// K7: stage2 BN+relu then layer2 matmul + stats. grid=60 (8 pos), block=128
__global__ void k7_s2l2(const float* __restrict__ g0, const float* __restrict__ b0,
                        const float* __restrict__ w1, float* __restrict__ ws) {
    int p0 = blockIdx.x*8, o = threadIdx.x;
    __shared__ float vls[8*128];
    float mean = ws[WS_ST2A+o]/480.f;
    float var  = ws[WS_ST2A+128+o]/480.f - mean*mean;
    float s = g0[o]*rsqrtf(var+EPS);
    float t = b0[o] - mean*s;
    for (int pp = 0; pp < 8; pp++)
        vls[pp*128+o] = fmaxf(fmaf(s, ws[WS_H2A+(p0+pp)*128+o], t), 0.f);
    __syncthreads();
    float sum=0.f, sq=0.f;
    for (int pp = 0; pp < 8; pp++) {
        float acc = 0.f;
        for (int i = 0; i < 128; i++) acc = fmaf(w1[o*128+i], vls[pp*128+i], acc);
        ws[WS_H2B+(p0+pp)*128+o] = acc;
        sum += acc; sq = fmaf(acc,acc,sq);
    }
    atomicAdd(&ws[WS_ST2B+o], sum);
    atomicAdd(&ws[WS_ST2B+128+o], sq);
}

// K8: lf2 = max_j relu(BN(h2)); build feats3. grid=32, block=128
__global__ void k8_build3(const float* __restrict__ g1, const float* __restrict__ b1,
                          float* __restrict__ ws) {
    int b = blockIdx.x, o = threadIdx.x;
    float mean = ws[WS_ST2B+o]/480.f;
    float var  = ws[WS_ST2B+128+o]/480.f - mean*mean;
    float s = g1[o]*rsqrtf(var+EPS);
    float t = b1[o] - mean*s;
    for (int s5 = 0; s5 < 5; s5++) {
        float m = -1e30f;
        for (int j = 0; j < 3; j++) {
            float v = fmaxf(fmaf(s, ws[WS_H2B+((b*5+s5)*3+j)*128+o], t), 0.f);
            m = fmaxf(m, v);
        }
        ws[WS_F3 + (b*5+s5)*131 + 3 + o] = m;
    }
    if (o < 15) {
        int s5 = o/3, i = o%3;
        ws[WS_F3 + (b*5+s5)*131 + i] = ws[WS_C2+b*15+o] - ws[WS_C3+b*3+i];
    }
}

// K9: stage3 layer1. grid=40 (4 pos), block=256
__global__ void k9_s3l1(const float* __restrict__ w, float* __restrict__ ws) {
    int p0 = blockIdx.x*4, o = threadIdx.x;
    float sum=0.f, sq=0.f;
    for (int pp = 0; pp < 4; pp++) {
        int p = p0+pp;
        float acc = 0.f;
        for (int c = 0; c < 131; c++) acc = fmaf(w[o*131+c], ws[WS_F3+p*131+c], acc);
        ws[WS_H3A + p*256 + o] = acc;
        sum += acc; sq = fmaf(acc,acc,sq);
    }
    atomicAdd(&ws[WS_ST3A+o], sum);
    atomicAdd(&ws[WS_ST3A+256+o], sq);
}

// K10: stage3 BN+relu + layer2. grid=40 (4 pos), block=256
__global__ void k10_s3l2(const float* __restrict__ g0, const float* __restrict__ b0,
                         const float* __restrict__ w1, float* __restrict__ ws) {
    int p0 = blockIdx.x*4, o = threadIdx.x;
    __shared__ float vls[4*256];
    float mean = ws[WS_ST3A+o]/160.f;
    float var  = ws[WS_ST3A+256+o]/160.f - mean*mean;
    float s = g0[o]*rsqrtf(var+EPS);
    float t = b0[o] - mean*s;
    for (int pp = 0; pp < 4; pp++)
        vls[pp*256+o] = fmaxf(fmaf(s, ws[WS_H3A+(p0+pp)*256+o], t), 0.f);
    __syncthreads();
    float sum=0.f, sq=0.f;
    for (int pp = 0; pp < 4; pp++) {
        float acc = 0.f;
        for (int i = 0; i < 256; i++) acc = fmaf(w1[o*256+i], vls[pp*256+i], acc);
        ws[WS_H3B+(p0+pp)*256+o] = acc;
        sum += acc; sq = fmaf(acc,acc,sq);
    }
    atomicAdd(&ws[WS_ST3B+o], sum);
    atomicAdd(&ws[WS_ST3B+256+o], sq);
}

// K11: gf = max_jj relu(BN(h2)). grid=32, block=256
__global__ void k11_gf(const float* __restrict__ g1, const float* __restrict__ b1,
                       const float* __restrict__ ws, float* __restrict__ out) {
    int b = blockIdx.x, o = threadIdx.x;
    float mean = ws[WS_ST3B+o]/160.f;
    float var  = ws[WS_ST3B+256+o]/160.f - mean*mean;
    float s = g1[o]*rsqrtf(var+EPS);
    float t = b1[o] - mean*s;
    float m = -1e30f;
    for (int jj = 0; jj < 5; jj++)
        m = fmaxf(m, fmaxf(fmaf(s, ws[WS_H3B+(b*5+jj)*256+o], t), 0.f));
    out[b*256+o] = m;
}

extern "C" void kernel_launch(void* const* d_in, const int* in_sizes, int n_in,
                              void* d_out, int out_size, void* d_ws, size_t ws_size,
                              hipStream_t stream) {
    (void)in_sizes; (void)n_in; (void)out_size; (void)ws_size;
    const float* x   = (const float*)d_in[0];
    const float* w00 = (const float*)d_in[1];
    const float* g00 = (const float*)d_in[2];
    const float* b00 = (const float*)d_in[3];
    const float* w01 = (const float*)d_in[4];
    const float* g01 = (const float*)d_in[5];
    const float* b01 = (const float*)d_in[6];
    const float* w10 = (const float*)d_in[7];
    const float* g10 = (const float*)d_in[8];
    const float* b10 = (const float*)d_in[9];
    const float* w11 = (const float*)d_in[10];
    const float* g11 = (const float*)d_in[11];
    const float* b11 = (const float*)d_in[12];
    const float* w20 = (const float*)d_in[13];
    const float* g20 = (const float*)d_in[14];
    const float* b20 = (const float*)d_in[15];
    const float* w21 = (const float*)d_in[16];
    const float* g21 = (const float*)d_in[17];
    const float* b21 = (const float*)d_in[18];
    float* out = (float*)d_out;
    float* ws  = (float*)d_ws;

    hipMemsetAsync(ws, 0, WS_ZERON*sizeof(float), stream);
    k1_pass1 <<<NBG, 256, 0, stream>>>(x, ws, out);
    k3_mfma  <<<NBG*SPLITS, 256, 0, stream>>>(x, w00, b00, g00, w01, ws);
    k45_final<<<BB, 128, 0, stream>>>(g01, b01, ws, out);
    k6_s2l1  <<<120, 128, 0, stream>>>(w10, ws);
    k7_s2l2  <<<60, 128, 0, stream>>>(g10, b10, w11, ws);
    k8_build3<<<BB, 128, 0, stream>>>(g11, b11, ws);
    k9_s3l1  <<<40, 256, 0, stream>>>(w20, ws);
    k10_s3l2 <<<40, 256, 0, stream>>>(g20, b20, w21, ws);
    k11_gf   <<<BB, 256, 0, stream>>>(g21, b21, ws, out);
}